// Round 11
// baseline (41.678 us; speedup 1.0000x reference)
//
#include <hip/hip_runtime.h>
#include <math.h>

// Problem constants (reference is fixed-shape).
#define B_ 16
#define N_ 2048
#define D_ 128

typedef __attribute__((ext_vector_type(8))) short bf16x8;   // 8 bf16 = 4 VGPRs
typedef __attribute__((ext_vector_type(4))) float f32x4;

__device__ __forceinline__ unsigned short f2bf(float f) {
    unsigned u = __float_as_uint(f);
    u += 0x7FFFu + ((u >> 16) & 1u);
    return (unsigned short)(u >> 16);
}

__device__ __forceinline__ unsigned minkey(float f) {
    // order-preserving uint encoding of float (for atomicMin): exact, assoc.
    unsigned u = __float_as_uint(f);
    return u ^ ((unsigned)((int)u >> 31) | 0x80000000u);
}

// Fragment-order element offset within a 128x128 bf16 tile: one MFMA
// fragment-read (fixed fragment group g) = 64 lanes x 16 B CONTIGUOUS (1 KB).
__device__ __forceinline__ int frag_off(int c, int k) {
    return ((((k >> 5) * 8 + (c >> 6) * 4 + ((c >> 4) & 3)) * 64
             + ((k >> 3) & 3) * 16 + (c & 15)) * 8) + (k & 7);
}

// ---------------------------------------------------------------------------
// K1: fp32 -> bf16 fragment-ordered tiles + fp32 squared norms + per-call
// re-init of pmk / fincnt (harness never re-poisons between replays).
// ---------------------------------------------------------------------------
__global__ __launch_bounds__(256) void prep_kernel(
        const float* __restrict__ X, unsigned short* __restrict__ Xs,
        float* __restrict__ sqn, unsigned* __restrict__ pmk,
        unsigned* __restrict__ fincnt) {
    int wv = threadIdx.x >> 6, ln = threadIdx.x & 63;
    int row0 = blockIdx.x * 16 + wv * 4;
    #pragma unroll
    for (int i = 0; i < 4; ++i) {
        int row = row0 + i;
        const float* src = X + (size_t)row * D_;
        float2 v = *(const float2*)(src + ln * 2);
        unsigned short h0 = f2bf(v.x), h1 = f2bf(v.y);
        float f0 = __uint_as_float((unsigned)h0 << 16);
        float f1 = __uint_as_float((unsigned)h1 << 16);
        float s = f0 * f0 + f1 * f1;
        #pragma unroll
        for (int o = 32; o; o >>= 1) s += __shfl_xor(s, o, 64);
        int c   = row & 127;
        int off = frag_off(c, ln * 2);     // k&7 even -> bf16 pair stays intact
        *(unsigned*)(Xs + (((size_t)(row >> 7)) << 14) + off) =
            (unsigned)h0 | ((unsigned)h1 << 16);
        if (ln == 0) { sqn[row] = s; pmk[row] = 0xFFFFFFFFu; }
    }
    if (blockIdx.x == 0 && threadIdx.x == 0) *fincnt = 0u;
}

// ---------------------------------------------------------------------------
// K2: fused Gram + row-min — OCCUPANCY EXPERIMENT.  Rounds 2/5/7/10 all
// plateau at nnd ~28-32 us with EXACTLY 8 waves/CU, regardless of structure
// (LDS dbuf / LDS frag-order / reg-prefetch); R8 counters prove waves sit in
// memory waits ~80% of cycles at full clock.  Latency-bound => time ~ 1/TLP.
// This round: 16 waves/CU.  Grid 1024 = ONE round at 4 WGs/CU (no LDS,
// VGPR <= 128 forced by __launch_bounds__(256,4)).  Wave owns 32 i-rows
// (A-frags 32 VGPR); same flat 32-sub-step loop as R10 with 1-step-ahead
// register prefetch of 4 B-fragments (1 KB coalesced each, L1-shared within
// the WG); 8 MFMAs per sub-step.  Raw s_barrier every 8 steps keeps waves
// lockstep for L1 reuse.  No LDS, no __syncthreads, no fences.
// Grid 1024 = b(16) x it(16: 128-row i-tile) x jo(4: 512-col quarter).
// Row-mins merge via uint-keyed atomicMin (exact, associative, determ.).
// ---------------------------------------------------------------------------
__global__ __launch_bounds__(256, 4) void nnd_kernel(
        const unsigned short* __restrict__ Xs, const float* __restrict__ sqn,
        unsigned* __restrict__ pmk) {
    // XCD-chunked remap (1024 = 8 x 128, bijective): 128 consecutive ids per
    // XCD -> 2 batches (1 MB of Xs) per XCD L2.  Whole grid co-resident.
    int wg  = (int)blockIdx.x;
    int id  = (wg & 7) * 128 + (wg >> 3);
    int b   = id >> 6;           // 64 ids per batch
    int sub = id & 63;
    int it  = sub >> 2;          // 128-row i-tile (16 per batch)
    int jo  = sub & 3;           // 512-col j-quarter (4 tiles of 128)

    int tid = threadIdx.x, wv = tid >> 6, ln = tid & 63;
    int lr = ln & 15;                 // fragment row/col lane index
    int kg = (ln >> 4) * 8;           // A fragment k-group offset
    int rg = (ln >> 4) * 4;           // C/D fragment row-group offset

    const unsigned short* Xb  = Xs  + (size_t)b * N_ * D_;
    const float*          sqb = sqn + b * N_;
    int ibase = it * 128 + wv * 32;   // this wave's first i-row

    // A fragments: 32 rows x K=128, registers for the whole sweep.
    bf16x8 Af[2][4];
    #pragma unroll
    for (int m = 0; m < 2; ++m) {
        int r = ibase + m * 16 + lr;
        const unsigned short* tp = Xb + (((size_t)(r >> 7)) << 14);
        int c = r & 127;
        #pragma unroll
        for (int ks = 0; ks < 4; ++ks)
            Af[m][ks] = *(const bf16x8*)(tp + frag_off(c, ks * 32 + kg));
    }

    float rmin[8];
    #pragma unroll
    for (int q = 0; q < 8; ++q) rmin[q] = 1e30f;
    const f32x4 zero4 = {0.f, 0.f, 0.f, 0.f};

    f32x4 acc[2][2];                 // constant-indexed after full unroll
    bf16x8 c0, c1, c2, c3, x0, x1, x2, x3;
    float nj0 = 0.f, nj1 = 0.f;

    // Preload sub-step 0 (t=0, half=0, np=0, kh=0): groups g = 0,1,8,9.
    {
        const unsigned short* tp = Xb + ((size_t)(jo * 4) << 14);
        c0 = *(const bf16x8*)(tp + ((size_t)(0 * 64 + ln) * 8));
        c1 = *(const bf16x8*)(tp + ((size_t)(1 * 64 + ln) * 8));
        c2 = *(const bf16x8*)(tp + ((size_t)(8 * 64 + ln) * 8));
        c3 = *(const bf16x8*)(tp + ((size_t)(9 * 64 + ln) * 8));
    }

    #pragma unroll
    for (int s = 0; s < 32; ++s) {
        const int t    = s >> 3;
        const int half = (s >> 2) & 1;
        const int np   = (s >> 1) & 1;
        const int kh   = s & 1;
        const int jt   = jo * 4 + t;

        // Prefetch sub-step s+1's 4 B-fragments (issued before the MFMAs).
        if (s + 1 < 32) {
            const int s1 = s + 1;
            const int t1 = s1 >> 3, h1 = (s1 >> 2) & 1;
            const int p1 = (s1 >> 1) & 1, k1 = s1 & 1;
            const unsigned short* tp1 = Xb + ((size_t)(jo * 4 + t1) << 14);
            const int gl = (k1 * 2) * 8 + h1 * 4 + p1 * 2;   // ks-lo group
            x0 = *(const bf16x8*)(tp1 + ((size_t)((gl    ) * 64 + ln) * 8));
            x1 = *(const bf16x8*)(tp1 + ((size_t)((gl + 1) * 64 + ln) * 8));
            x2 = *(const bf16x8*)(tp1 + ((size_t)((gl + 8) * 64 + ln) * 8));
            x3 = *(const bf16x8*)(tp1 + ((size_t)((gl + 9) * 64 + ln) * 8));
        }
        if (kh == 0) {   // column norms for this (t,half,np), used at kh==1
            nj0 = sqb[jt * 128 + (half * 4 + np * 2 + 0) * 16 + lr];
            nj1 = sqb[jt * 128 + (half * 4 + np * 2 + 1) * 16 + lr];
        }

        // 8 MFMAs: ks = kh*2 (c0:n0, c1:n1), ks = kh*2+1 (c2, c3).
        #pragma unroll
        for (int m = 0; m < 2; ++m) {
            acc[m][0] = __builtin_amdgcn_mfma_f32_16x16x32_bf16(
                Af[m][kh * 2], c0, kh ? acc[m][0] : zero4, 0, 0, 0);
            acc[m][1] = __builtin_amdgcn_mfma_f32_16x16x32_bf16(
                Af[m][kh * 2], c1, kh ? acc[m][1] : zero4, 0, 0, 0);
        }
        #pragma unroll
        for (int m = 0; m < 2; ++m) {
            acc[m][0] = __builtin_amdgcn_mfma_f32_16x16x32_bf16(
                Af[m][kh * 2 + 1], c2, acc[m][0], 0, 0, 0);
            acc[m][1] = __builtin_amdgcn_mfma_f32_16x16x32_bf16(
                Af[m][kh * 2 + 1], c3, acc[m][1], 0, 0, 0);
        }

        if (kh == 1) {   // epilogue: fold min_j (n_j - 2 g) for this n-pair
            const bool dtile = (jt == it);
            if (!dtile) {
                #pragma unroll
                for (int m = 0; m < 2; ++m)
                    #pragma unroll
                    for (int rr = 0; rr < 4; ++rr) {
                        float t0 = fmaf(-2.f, acc[m][0][rr], nj0);
                        float t1 = fmaf(-2.f, acc[m][1][rr], nj1);
                        rmin[m * 4 + rr] =
                            fminf(rmin[m * 4 + rr], fminf(t0, t1));
                    }
            } else {
                #pragma unroll
                for (int m = 0; m < 2; ++m)
                    #pragma unroll
                    for (int rr = 0; rr < 4; ++rr) {
                        int ir = ibase + m * 16 + rg + rr;       // global row
                        int jc = jt * 128 + (half * 4 + np * 2) * 16 + lr;
                        float t0 = (ir == jc)      ? 1e30f
                                   : fmaf(-2.f, acc[m][0][rr], nj0);
                        float t1 = (ir == jc + 16) ? 1e30f
                                   : fmaf(-2.f, acc[m][1][rr], nj1);
                        rmin[m * 4 + rr] =
                            fminf(rmin[m * 4 + rr], fminf(t0, t1));
                    }
            }
        }

        c0 = x0; c1 = x1; c2 = x2; c3 = x3;

        // Tile boundary: raw s_barrier (exec sync only, no memory drain) to
        // keep the WG's 4 waves lockstep so identical B-reads hit L1.
        if ((s & 7) == 7 && s != 31) __builtin_amdgcn_s_barrier();
    }

    // Min across the 16 column-lanes, then one atomicMin per row.
    #pragma unroll
    for (int o = 1; o < 16; o <<= 1)
        #pragma unroll
        for (int q = 0; q < 8; ++q)
            rmin[q] = fminf(rmin[q], __shfl_xor(rmin[q], o, 64));
    if (lr == 0) {
        #pragma unroll
        for (int m = 0; m < 2; ++m)
            #pragma unroll
            for (int rr = 0; rr < 4; ++rr) {
                int row = ibase + m * 16 + rg + rr;
                atomicMin(pmk + b * N_ + row, minkey(rmin[m * 4 + rr]));
            }
    }
}

// ---------------------------------------------------------------------------
// K3: decode keys -> nnd; mean / unbiased std / CV.  64 WGs x 512 thr (one
// pmk load per thread — round-8 lesson: a single-WG reader serializes 32K
// high-latency loads = +40 us).  Last WG sums the 64 slots.
// ---------------------------------------------------------------------------
__global__ __launch_bounds__(512) void finalize_kernel(
        const unsigned* __restrict__ pmk, const float* __restrict__ sqn,
        double* __restrict__ slots, unsigned* __restrict__ fincnt,
        float* __restrict__ out) {
    const int M = B_ * N_;
    int r = blockIdx.x * 512 + (int)threadIdx.x;
    unsigned key = pmk[r];
    unsigned u   = (key & 0x80000000u) ? (key ^ 0x80000000u) : ~key;
    float d2 = sqn[r] + __uint_as_float(u);
    float x32 = sqrtf(fmaxf(d2, 0.f));       // reference uses f32 sqrt too
    double x = (double)x32;
    double s1 = x, s2 = x * x;
    #pragma unroll
    for (int o = 32; o; o >>= 1) {
        s1 += __shfl_down(s1, o, 64);
        s2 += __shfl_down(s2, o, 64);
    }
    __shared__ double a1[8], a2[8];
    int wv = threadIdx.x >> 6, ln = threadIdx.x & 63;
    if (ln == 0) { a1[wv] = s1; a2[wv] = s2; }
    __syncthreads();
    if (threadIdx.x == 0) {
        double S1 = 0.0, S2 = 0.0;
        #pragma unroll
        for (int w = 0; w < 8; ++w) { S1 += a1[w]; S2 += a2[w]; }
        slots[blockIdx.x * 2]     = S1;
        slots[blockIdx.x * 2 + 1] = S2;
        __threadfence();
        unsigned old = atomicAdd(fincnt, 1u);
        if (old == 63u) {
            double T1 = 0.0, T2 = 0.0;
            for (int w = 0; w < 64; ++w) {
                T1 += __hip_atomic_load(&slots[w * 2],     __ATOMIC_RELAXED,
                                        __HIP_MEMORY_SCOPE_AGENT);
                T2 += __hip_atomic_load(&slots[w * 2 + 1], __ATOMIC_RELAXED,
                                        __HIP_MEMORY_SCOPE_AGENT);
            }
            double mean = T1 / M;
            double var  = (T2 - T1 * T1 / M) / (M - 1);
            double stdv = var > 0.0 ? sqrt(var) : 0.0;
            double cv   = (mean > 1e-8) ? stdv / fmax(mean, 1e-8) : 0.0;
            out[0] = (float)mean;
            out[1] = (float)stdv;
            out[2] = (float)cv;
        }
    }
}

extern "C" void kernel_launch(void* const* d_in, const int* in_sizes, int n_in,
                              void* d_out, int out_size, void* d_ws, size_t ws_size,
                              hipStream_t stream) {
    const float* X = (const float*)d_in[0];
    const size_t XS_BYTES = (size_t)B_ * N_ * D_ * 2;        // 8 MB
    char* ws = (char*)d_ws;
    unsigned short* Xs     = (unsigned short*)ws;
    float*          sqn    = (float*)(ws + XS_BYTES);
    unsigned*       pmk    = (unsigned*)(ws + XS_BYTES + (size_t)B_ * N_ * 4);
    double*         slots  = (double*)(ws + XS_BYTES + (size_t)B_ * N_ * 8);
    unsigned*       fincnt = (unsigned*)(ws + XS_BYTES + (size_t)B_ * N_ * 8 + 1024);
    float*          out    = (float*)d_out;

    prep_kernel<<<B_ * N_ / 16, 256, 0, stream>>>(X, Xs, sqn, pmk, fincnt);
    nnd_kernel<<<1024, 256, 0, stream>>>(Xs, sqn, pmk);
    finalize_kernel<<<B_ * N_ / 512, 512, 0, stream>>>(pmk, sqn, slots, fincnt, out);
}

// Round 12
// 39.168 us; speedup vs baseline: 1.0641x; 1.0641x over previous
//
#include <hip/hip_runtime.h>
#include <math.h>

// Problem constants (reference is fixed-shape).
#define B_ 16
#define N_ 2048
#define D_ 128

typedef __attribute__((ext_vector_type(8))) short bf16x8;   // 8 bf16 = 4 VGPRs
typedef __attribute__((ext_vector_type(4))) float f32x4;

__device__ __forceinline__ unsigned short f2bf(float f) {
    unsigned u = __float_as_uint(f);
    u += 0x7FFFu + ((u >> 16) & 1u);
    return (unsigned short)(u >> 16);
}

__device__ __forceinline__ unsigned minkey(float f) {
    // order-preserving uint encoding of float (for atomicMin): exact, assoc.
    unsigned u = __float_as_uint(f);
    return u ^ ((unsigned)((int)u >> 31) | 0x80000000u);
}

// Fragment-order element offset within a 128x128 bf16 tile: one MFMA
// fragment-read (fixed fragment group g) = 64 lanes x 16 B CONTIGUOUS (1 KB).
__device__ __forceinline__ int frag_off(int c, int k) {
    return ((((k >> 5) * 8 + (c >> 6) * 4 + ((c >> 4) & 3)) * 64
             + ((k >> 3) & 3) * 16 + (c & 15)) * 8) + (k & 7);
}

// ---------------------------------------------------------------------------
// K1: fp32 -> bf16 fragment-ordered tiles + fp32 squared norms + per-call
// re-init of pmk / fincnt (harness never re-poisons between replays).
// ---------------------------------------------------------------------------
__global__ __launch_bounds__(256) void prep_kernel(
        const float* __restrict__ X, unsigned short* __restrict__ Xs,
        float* __restrict__ sqn, unsigned* __restrict__ pmk,
        unsigned* __restrict__ fincnt) {
    int wv = threadIdx.x >> 6, ln = threadIdx.x & 63;
    int row0 = blockIdx.x * 16 + wv * 4;
    #pragma unroll
    for (int i = 0; i < 4; ++i) {
        int row = row0 + i;
        const float* src = X + (size_t)row * D_;
        float2 v = *(const float2*)(src + ln * 2);
        unsigned short h0 = f2bf(v.x), h1 = f2bf(v.y);
        float f0 = __uint_as_float((unsigned)h0 << 16);
        float f1 = __uint_as_float((unsigned)h1 << 16);
        float s = f0 * f0 + f1 * f1;
        #pragma unroll
        for (int o = 32; o; o >>= 1) s += __shfl_xor(s, o, 64);
        int c   = row & 127;
        int off = frag_off(c, ln * 2);     // k&7 even -> bf16 pair stays intact
        *(unsigned*)(Xs + (((size_t)(row >> 7)) << 14) + off) =
            (unsigned)h0 | ((unsigned)h1 << 16);
        if (ln == 0) { sqn[row] = s; pmk[row] = 0xFFFFFFFFu; }
    }
    if (blockIdx.x == 0 && threadIdx.x == 0) *fincnt = 0u;
}

// ---------------------------------------------------------------------------
// K2: fused Gram + row-min — I-CACHE EXPERIMENT (single change vs round 10).
// All prior nnd variants (R2..R11, all ~30 us) share one trait: fully
// unrolled straight-line bodies of 3-6K instructions (30-50 KB code) >> 32 KB
// L1I, streamed with ZERO reuse by every wave — an instruction-fetch stall
// invisible to VALU/MFMA/FETCH counters (code stays L2-resident), consistent
// with the universal "everything idle at full clock" profiles and with 2x
// occupancy making things WORSE (R11: more waves streaming more code).
// Fix under test: `#pragma unroll 2` -> 16 iterations of a ~2 KB body
// (L1I-resident after iter 1).  kh parity is static per unrolled half, so
// acc/Af indexing stays compile-time constant (no scratch).  Everything else
// is byte-identical to round 10 (512 WGs one round @ 2 WG/CU, 64 rows/wave,
// reg-staged B with 1-step-ahead prefetch, raw s_barrier per tile).
// ---------------------------------------------------------------------------
__global__ __launch_bounds__(256, 2) void nnd_kernel(
        const unsigned short* __restrict__ Xs, const float* __restrict__ sqn,
        unsigned* __restrict__ pmk) {
    // XCD-chunked remap (512 = 8 x 64, bijective): 64 consecutive ids per
    // XCD -> 2 batches (1 MB of Xs) per XCD L2.  Whole grid co-resident.
    int wg  = (int)blockIdx.x;
    int id  = (wg & 7) * 64 + (wg >> 3);
    int b   = id >> 5;           // 32 ids per batch
    int sub = id & 31;
    int it  = sub >> 2;          // 256-row i-tile (8 per batch)
    int jo  = sub & 3;           // 512-col j-quarter (4 tiles of 128)

    int tid = threadIdx.x, wv = tid >> 6, ln = tid & 63;
    int lr = ln & 15;                 // fragment row/col lane index
    int kg = (ln >> 4) * 8;           // A fragment k-group offset
    int rg = (ln >> 4) * 4;           // C/D fragment row-group offset

    const unsigned short* Xb  = Xs  + (size_t)b * N_ * D_;
    const float*          sqb = sqn + b * N_;
    int ibase = it * 256 + wv * 64;   // this wave's first i-row

    // A fragments: 64 rows x K=128, registers for the whole sweep (coalesced
    // 1 KB loads from the fragment-ordered layout).
    bf16x8 Af[4][4];
    #pragma unroll
    for (int m = 0; m < 4; ++m) {
        int r = ibase + m * 16 + lr;
        const unsigned short* tp = Xb + (((size_t)(r >> 7)) << 14);
        int c = r & 127;
        #pragma unroll
        for (int ks = 0; ks < 4; ++ks)
            Af[m][ks] = *(const bf16x8*)(tp + frag_off(c, ks * 32 + kg));
    }

    float rmin[16];
    #pragma unroll
    for (int q = 0; q < 16; ++q) rmin[q] = 1e30f;
    const f32x4 zero4 = {0.f, 0.f, 0.f, 0.f};

    f32x4 acc[4][2];                 // constant-indexed (static kh per half)
    bf16x8 c0, c1, c2, c3, x0, x1, x2, x3;
    float nj0 = 0.f, nj1 = 0.f;

    // Preload sub-step 0 (t=0, half=0, np=0, kh=0): groups g = 0,1,8,9.
    {
        const unsigned short* tp = Xb + ((size_t)(jo * 4) << 14);
        c0 = *(const bf16x8*)(tp + ((size_t)(0 * 64 + ln) * 8));
        c1 = *(const bf16x8*)(tp + ((size_t)(1 * 64 + ln) * 8));
        c2 = *(const bf16x8*)(tp + ((size_t)(8 * 64 + ln) * 8));
        c3 = *(const bf16x8*)(tp + ((size_t)(9 * 64 + ln) * 8));
    }

    // 32 sub-steps, unrolled BY 2 ONLY: 16 looped iterations of an (even kh=0,
    // odd kh=1) pair.  Body ~2 KB -> L1I-resident; s-derived indices are
    // cheap wave-uniform SALU at runtime.
    #pragma unroll 2
    for (int s = 0; s < 32; ++s) {
        const int t    = s >> 3;
        const int half = (s >> 2) & 1;
        const int np   = (s >> 1) & 1;
        const int kh   = s & 1;               // static per unrolled half
        const int jt   = jo * 4 + t;

        // Prefetch sub-step s+1's 4 B-fragments (issued before the MFMAs).
        if (s + 1 < 32) {
            const int s1 = s + 1;
            const int t1 = s1 >> 3, h1 = (s1 >> 2) & 1;
            const int p1 = (s1 >> 1) & 1, k1 = s1 & 1;
            const unsigned short* tp1 = Xb + ((size_t)(jo * 4 + t1) << 14);
            const int gl = (k1 * 2) * 8 + h1 * 4 + p1 * 2;   // ks-lo group
            x0 = *(const bf16x8*)(tp1 + ((size_t)((gl    ) * 64 + ln) * 8));
            x1 = *(const bf16x8*)(tp1 + ((size_t)((gl + 1) * 64 + ln) * 8));
            x2 = *(const bf16x8*)(tp1 + ((size_t)((gl + 8) * 64 + ln) * 8));
            x3 = *(const bf16x8*)(tp1 + ((size_t)((gl + 9) * 64 + ln) * 8));
        }
        if (kh == 0) {   // column norms for this (t,half,np), used at kh==1
            nj0 = sqb[jt * 128 + (half * 4 + np * 2 + 0) * 16 + lr];
            nj1 = sqb[jt * 128 + (half * 4 + np * 2 + 1) * 16 + lr];
        }

        // 16 MFMAs: ks = kh*2 (c0:n0, c1:n1), ks = kh*2+1 (c2, c3).
        #pragma unroll
        for (int m = 0; m < 4; ++m) {
            acc[m][0] = __builtin_amdgcn_mfma_f32_16x16x32_bf16(
                Af[m][kh * 2], c0, kh ? acc[m][0] : zero4, 0, 0, 0);
            acc[m][1] = __builtin_amdgcn_mfma_f32_16x16x32_bf16(
                Af[m][kh * 2], c1, kh ? acc[m][1] : zero4, 0, 0, 0);
        }
        #pragma unroll
        for (int m = 0; m < 4; ++m) {
            acc[m][0] = __builtin_amdgcn_mfma_f32_16x16x32_bf16(
                Af[m][kh * 2 + 1], c2, acc[m][0], 0, 0, 0);
            acc[m][1] = __builtin_amdgcn_mfma_f32_16x16x32_bf16(
                Af[m][kh * 2 + 1], c3, acc[m][1], 0, 0, 0);
        }

        if (kh == 1) {   // epilogue: fold min_j (n_j - 2 g) for this n-pair
            const bool dtile = (jt >> 1) == it;
            if (!dtile) {
                #pragma unroll
                for (int m = 0; m < 4; ++m)
                    #pragma unroll
                    for (int rr = 0; rr < 4; ++rr) {
                        float t0 = fmaf(-2.f, acc[m][0][rr], nj0);
                        float t1 = fmaf(-2.f, acc[m][1][rr], nj1);
                        rmin[m * 4 + rr] =
                            fminf(rmin[m * 4 + rr], fminf(t0, t1));
                    }
            } else {
                #pragma unroll
                for (int m = 0; m < 4; ++m)
                    #pragma unroll
                    for (int rr = 0; rr < 4; ++rr) {
                        int ir = ibase + m * 16 + rg + rr;       // global row
                        int jc = jt * 128 + (half * 4 + np * 2) * 16 + lr;
                        float t0 = (ir == jc)      ? 1e30f
                                   : fmaf(-2.f, acc[m][0][rr], nj0);
                        float t1 = (ir == jc + 16) ? 1e30f
                                   : fmaf(-2.f, acc[m][1][rr], nj1);
                        rmin[m * 4 + rr] =
                            fminf(rmin[m * 4 + rr], fminf(t0, t1));
                    }
            }
        }

        c0 = x0; c1 = x1; c2 = x2; c3 = x3;

        // Tile boundary: raw s_barrier (exec sync only, no memory drain) to
        // keep the WG's 4 waves lockstep so identical B-reads hit L1.
        if ((s & 7) == 7 && s != 31) __builtin_amdgcn_s_barrier();
    }

    // Min across the 16 column-lanes, then one atomicMin per row.
    #pragma unroll
    for (int o = 1; o < 16; o <<= 1)
        #pragma unroll
        for (int q = 0; q < 16; ++q)
            rmin[q] = fminf(rmin[q], __shfl_xor(rmin[q], o, 64));
    if (lr == 0) {
        #pragma unroll
        for (int m = 0; m < 4; ++m)
            #pragma unroll
            for (int rr = 0; rr < 4; ++rr) {
                int row = ibase + m * 16 + rg + rr;
                atomicMin(pmk + b * N_ + row, minkey(rmin[m * 4 + rr]));
            }
    }
}

// ---------------------------------------------------------------------------
// K3: decode keys -> nnd; mean / unbiased std / CV.  64 WGs x 512 thr (one
// pmk load per thread — round-8 lesson: a single-WG reader serializes 32K
// high-latency loads = +40 us).  Last WG sums the 64 slots.
// ---------------------------------------------------------------------------
__global__ __launch_bounds__(512) void finalize_kernel(
        const unsigned* __restrict__ pmk, const float* __restrict__ sqn,
        double* __restrict__ slots, unsigned* __restrict__ fincnt,
        float* __restrict__ out) {
    const int M = B_ * N_;
    int r = blockIdx.x * 512 + (int)threadIdx.x;
    unsigned key = pmk[r];
    unsigned u   = (key & 0x80000000u) ? (key ^ 0x80000000u) : ~key;
    float d2 = sqn[r] + __uint_as_float(u);
    float x32 = sqrtf(fmaxf(d2, 0.f));       // reference uses f32 sqrt too
    double x = (double)x32;
    double s1 = x, s2 = x * x;
    #pragma unroll
    for (int o = 32; o; o >>= 1) {
        s1 += __shfl_down(s1, o, 64);
        s2 += __shfl_down(s2, o, 64);
    }
    __shared__ double a1[8], a2[8];
    int wv = threadIdx.x >> 6, ln = threadIdx.x & 63;
    if (ln == 0) { a1[wv] = s1; a2[wv] = s2; }
    __syncthreads();
    if (threadIdx.x == 0) {
        double S1 = 0.0, S2 = 0.0;
        #pragma unroll
        for (int w = 0; w < 8; ++w) { S1 += a1[w]; S2 += a2[w]; }
        slots[blockIdx.x * 2]     = S1;
        slots[blockIdx.x * 2 + 1] = S2;
        __threadfence();
        unsigned old = atomicAdd(fincnt, 1u);
        if (old == 63u) {
            double T1 = 0.0, T2 = 0.0;
            for (int w = 0; w < 64; ++w) {
                T1 += __hip_atomic_load(&slots[w * 2],     __ATOMIC_RELAXED,
                                        __HIP_MEMORY_SCOPE_AGENT);
                T2 += __hip_atomic_load(&slots[w * 2 + 1], __ATOMIC_RELAXED,
                                        __HIP_MEMORY_SCOPE_AGENT);
            }
            double mean = T1 / M;
            double var  = (T2 - T1 * T1 / M) / (M - 1);
            double stdv = var > 0.0 ? sqrt(var) : 0.0;
            double cv   = (mean > 1e-8) ? stdv / fmax(mean, 1e-8) : 0.0;
            out[0] = (float)mean;
            out[1] = (float)stdv;
            out[2] = (float)cv;
        }
    }
}

extern "C" void kernel_launch(void* const* d_in, const int* in_sizes, int n_in,
                              void* d_out, int out_size, void* d_ws, size_t ws_size,
                              hipStream_t stream) {
    const float* X = (const float*)d_in[0];
    const size_t XS_BYTES = (size_t)B_ * N_ * D_ * 2;        // 8 MB
    char* ws = (char*)d_ws;
    unsigned short* Xs     = (unsigned short*)ws;
    float*          sqn    = (float*)(ws + XS_BYTES);
    unsigned*       pmk    = (unsigned*)(ws + XS_BYTES + (size_t)B_ * N_ * 4);
    double*         slots  = (double*)(ws + XS_BYTES + (size_t)B_ * N_ * 8);
    unsigned*       fincnt = (unsigned*)(ws + XS_BYTES + (size_t)B_ * N_ * 8 + 1024);
    float*          out    = (float*)d_out;

    prep_kernel<<<B_ * N_ / 16, 256, 0, stream>>>(X, Xs, sqn, pmk, fincnt);
    nnd_kernel<<<512, 256, 0, stream>>>(Xs, sqn, pmk);
    finalize_kernel<<<B_ * N_ / 512, 512, 0, stream>>>(pmk, sqn, slots, fincnt, out);
}